// Round 2
// baseline (926.649 us; speedup 1.0000x reference)
//
#include <hip/hip_runtime.h>
#include <math.h>

// Problem constants (from reference): N nodes, D feat, H heads, E edges
#define NN 50000
#define DD 64
#define HH 8
#define EE 800000
#define NEG_SLOPE 0.2f

// ---- float <-> order-preserving uint (for atomicMax on float) ----
__device__ __forceinline__ unsigned ordf(float f) {
  unsigned u = __float_as_uint(f);
  return (u & 0x80000000u) ? ~u : (u | 0x80000000u);
}
__device__ __forceinline__ float unordf(unsigned u) {
  unsigned b = (u & 0x80000000u) ? (u & 0x7FFFFFFFu) : ~u;
  return __uint_as_float(b);
}

// K1: per-node scores  s_dst[n,h] = h_t[n,:]·att[h,0:64], s_src = ·att[h,64:128]
__global__ __launch_bounds__(256) void scores_kernel(
    const float* __restrict__ h_t, const float* __restrict__ att,
    float* __restrict__ s_dst, float* __restrict__ s_src) {
  __shared__ float hs[32 * 66];    // 32 nodes x 64, padded to 66 (bank conflicts)
  __shared__ float att_s[8 * 130]; // 8 heads x 128, padded to 130
  int tid = threadIdx.x;
  int node0 = blockIdx.x * 32;
  for (int q = tid; q < HH * 2 * DD; q += 256) {
    int h = q >> 7, k = q & 127;
    att_s[h * 130 + k] = att[q];
  }
  for (int q = tid; q < 32 * DD; q += 256) {
    int nl = q >> 6, d = q & 63;
    hs[nl * 66 + d] = (node0 + nl < NN) ? h_t[(size_t)(node0 + nl) * DD + d] : 0.0f;
  }
  __syncthreads();
  int nl = tid >> 3, h = tid & 7;
  int n = node0 + nl;
  float accd = 0.f, accs = 0.f;
#pragma unroll
  for (int d = 0; d < DD; ++d) {
    float hv = hs[nl * 66 + d];
    accd += hv * att_s[h * 130 + d];
    accs += hv * att_s[h * 130 + DD + d];
  }
  if (n < NN) {
    s_dst[n * HH + h] = accd;  // coalesced: index = node0*8 + tid
    s_src[n * HH + h] = accs;
  }
}

// K2: per-edge raw scores + leaky relu; atomic segment-max; degree counts
__global__ __launch_bounds__(256) void edgeA_kernel(
    const int* __restrict__ ei, const float* __restrict__ s_dst,
    const float* __restrict__ s_src, unsigned* __restrict__ emax_u,
    int* __restrict__ counts, float* __restrict__ evals) {
  int e = blockIdx.x * 256 + threadIdx.x;
  if (e >= EE) return;
  int sidx = ei[e];
  int didx = ei[EE + e];
  atomicAdd(&counts[didx], 1);
  const float4* sd = (const float4*)(s_dst + (size_t)didx * HH);
  const float4* ss = (const float4*)(s_src + (size_t)sidx * HH);
  float4 d0 = sd[0], d1 = sd[1], s0 = ss[0], s1 = ss[1];
  float v[8] = {d0.x + s0.x, d0.y + s0.y, d0.z + s0.z, d0.w + s0.w,
                d1.x + s1.x, d1.y + s1.y, d1.z + s1.z, d1.w + s1.w};
#pragma unroll
  for (int h = 0; h < 8; ++h) {
    v[h] = v[h] >= 0.f ? v[h] : NEG_SLOPE * v[h];
    atomicMax(&emax_u[(size_t)didx * 8 + h], ordf(v[h]));
  }
  float4* ev = (float4*)(evals + (size_t)e * 8);
  ev[0] = make_float4(v[0], v[1], v[2], v[3]);
  ev[1] = make_float4(v[4], v[5], v[6], v[7]);
}

// K3: exclusive scan of counts -> row_start (single block, shfl-based)
__global__ __launch_bounds__(256) void scan_kernel(const int* __restrict__ counts,
                                                   int* __restrict__ row_start) {
  __shared__ int wtot[4];
  int tid = threadIdx.x, lane = tid & 63, wid = tid >> 6;
  int carry = 0;
  const int CHUNK = 256 * 16;  // 4096 elements per pass
  for (int base = 0; base < NN; base += CHUNK) {
    int i0 = base + tid * 16;
    int loc[16];
    int tot = 0;
#pragma unroll
    for (int k = 0; k < 16; ++k) {
      int idx = i0 + k;
      int v = (idx < NN) ? counts[idx] : 0;
      tot += v;
      loc[k] = tot;  // per-thread inclusive
    }
    int incl = tot;
    for (int off = 1; off < 64; off <<= 1) {
      int u = __shfl_up(incl, off);
      if (lane >= off) incl += u;
    }
    if (lane == 63) wtot[wid] = incl;
    __syncthreads();
    int wpre = 0;
    for (int w = 0; w < wid; ++w) wpre += wtot[w];
    int chunk_tot = wtot[0] + wtot[1] + wtot[2] + wtot[3];
    int thread_excl = carry + wpre + (incl - tot);
#pragma unroll
    for (int k = 0; k < 16; ++k) {
      int idx = i0 + k;
      int prev = (k == 0) ? 0 : loc[k - 1];
      if (idx < NN) row_start[idx] = thread_excl + prev;
    }
    carry += chunk_tot;
    __syncthreads();  // before wtot is overwritten next pass
  }
  if (tid == 0) row_start[NN] = carry;  // == EE
}

// K4: ex = exp(e - emax[dst]); atomic denom; CSR bucket fill
__global__ __launch_bounds__(256) void edgeB_kernel(
    const int* __restrict__ ei, const unsigned* __restrict__ emax_u,
    float* __restrict__ evals, float* __restrict__ denom,
    const int* __restrict__ row_start, int* __restrict__ fill_ctr,
    int* __restrict__ sorted_e) {
  int e = blockIdx.x * 256 + threadIdx.x;
  if (e >= EE) return;
  int didx = ei[EE + e];
  float4* ev = (float4*)(evals + (size_t)e * 8);
  float4 v0 = ev[0], v1 = ev[1];
  float v[8] = {v0.x, v0.y, v0.z, v0.w, v1.x, v1.y, v1.z, v1.w};
#pragma unroll
  for (int h = 0; h < 8; ++h) {
    float m = unordf(emax_u[(size_t)didx * 8 + h]);
    float x = expf(v[h] - m);
    v[h] = x;
    atomicAdd(&denom[(size_t)didx * 8 + h], x);
  }
  ev[0] = make_float4(v[0], v[1], v[2], v[3]);
  ev[1] = make_float4(v[4], v[5], v[6], v[7]);
  int pos = atomicAdd(&fill_ctr[didx], 1);
  sorted_e[row_start[didx] + pos] = e;
}

// K5: one block per dst node: alpha-weighted accumulate of h_t[src], ELU, store.
__global__ __launch_bounds__(256) void agg_kernel(
    const int* __restrict__ ei, const float* __restrict__ h_t,
    const float* __restrict__ evals, const float* __restrict__ denom,
    const int* __restrict__ row_start, const int* __restrict__ sorted_e,
    float* __restrict__ out) {
  int n = blockIdx.x;
  int tid = threadIdx.x;
  __shared__ float rd[8];
  __shared__ int src_s[32];
  __shared__ float alpha_s[32][8];
  int beg = row_start[n], end = row_start[n + 1];
  if (tid < 8) {
    float dn = denom[n * 8 + tid];
    rd[tid] = (dn > 0.f) ? 1.0f / dn : 0.f;
  }
  __syncthreads();
  float acc0 = 0.f, acc1 = 0.f;
  int h0 = tid >> 6;   // 0..3 ; second element is h0+4
  int d = tid & 63;
  for (int b = beg; b < end; b += 32) {
    int cnt = min(32, end - b);
    if (tid < cnt * 8) {
      int i = tid >> 3, h = tid & 7;
      int eid = sorted_e[b + i];
      alpha_s[i][h] = evals[(size_t)eid * 8 + h] * rd[h];
      if (h == 0) src_s[i] = ei[eid];  // src index of edge
    }
    __syncthreads();
    for (int i = 0; i < cnt; ++i) {
      float hv = h_t[(size_t)src_s[i] * 64 + d];  // L1/L2 resident
      acc0 += hv * alpha_s[i][h0];
      acc1 += hv * alpha_s[i][h0 + 4];
    }
    __syncthreads();
  }
  float r0 = acc0 > 0.f ? acc0 : expm1f(acc0);
  float r1 = acc1 > 0.f ? acc1 : expm1f(acc1);
  out[(size_t)n * 512 + tid] = r0;
  out[(size_t)n * 512 + 256 + tid] = r1;
}

extern "C" void kernel_launch(void* const* d_in, const int* in_sizes, int n_in,
                              void* d_out, int out_size, void* d_ws, size_t ws_size,
                              hipStream_t stream) {
  const float* h_t = (const float*)d_in[0];
  const int* ei = (const int*)d_in[1];   // [2, E] int32: row0 = src, row1 = dst
  const float* att = (const float*)d_in[2];
  float* out = (float*)d_out;

  char* ws = (char*)d_ws;
  size_t off = 0;
  auto alloc = [&](size_t bytes) {
    size_t cur = off;
    off += (bytes + 255) & ~(size_t)255;
    return cur;
  };
  float* s_dst = (float*)(ws + alloc((size_t)NN * HH * 4));
  float* s_src = (float*)(ws + alloc((size_t)NN * HH * 4));
  size_t zero_off = off;  // everything below here through fill_ctr gets zeroed
  unsigned* emax_u = (unsigned*)(ws + alloc((size_t)NN * HH * 4));
  float* denom = (float*)(ws + alloc((size_t)NN * HH * 4));
  int* counts = (int*)(ws + alloc((size_t)NN * 4));
  int* fill_ctr = (int*)(ws + alloc((size_t)NN * 4));
  size_t zero_bytes = off - zero_off;
  float* evals = (float*)(ws + alloc((size_t)EE * HH * 4));
  int* row_start = (int*)(ws + alloc((size_t)(NN + 1) * 4));
  int* sorted_e = (int*)(ws + alloc((size_t)EE * 4));

  hipMemsetAsync(ws + zero_off, 0, zero_bytes, stream);
  scores_kernel<<<(NN + 31) / 32, 256, 0, stream>>>(h_t, att, s_dst, s_src);
  edgeA_kernel<<<(EE + 255) / 256, 256, 0, stream>>>(ei, s_dst, s_src, emax_u,
                                                     counts, evals);
  scan_kernel<<<1, 256, 0, stream>>>(counts, row_start);
  edgeB_kernel<<<(EE + 255) / 256, 256, 0, stream>>>(ei, emax_u, evals, denom,
                                                     row_start, fill_ctr, sorted_e);
  agg_kernel<<<NN, 256, 0, stream>>>(ei, h_t, evals, denom, row_start, sorted_e,
                                     out);
}

// Round 3
// 448.635 us; speedup vs baseline: 2.0655x; 2.0655x over previous
//
#include <hip/hip_runtime.h>
#include <math.h>

// Problem constants (from reference): N nodes, D feat, H heads, E edges
#define NN 50000
#define DD 64
#define HH 8
#define EE 800000
#define NEG_SLOPE 0.2f
#define CAP 128  // per-node cached-degree capacity (avg degree = 16)

// K1: per-node scores  s_dst[n,h] = h_t[n,:]·att[h,0:64], s_src = ·att[h,64:128]
__global__ __launch_bounds__(256) void scores_kernel(
    const float* __restrict__ h_t, const float* __restrict__ att,
    float* __restrict__ s_dst, float* __restrict__ s_src) {
  __shared__ float hs[32 * 66];    // 32 nodes x 64, padded (bank conflicts)
  __shared__ float att_s[8 * 130]; // 8 heads x 128, padded
  int tid = threadIdx.x;
  int node0 = blockIdx.x * 32;
  for (int q = tid; q < HH * 2 * DD; q += 256) {
    int h = q >> 7, k = q & 127;
    att_s[h * 130 + k] = att[q];
  }
  for (int q = tid; q < 32 * DD; q += 256) {
    int nl = q >> 6, d = q & 63;
    hs[nl * 66 + d] = (node0 + nl < NN) ? h_t[(size_t)(node0 + nl) * DD + d] : 0.0f;
  }
  __syncthreads();
  int nl = tid >> 3, h = tid & 7;
  int n = node0 + nl;
  float accd = 0.f, accs = 0.f;
#pragma unroll
  for (int d = 0; d < DD; ++d) {
    float hv = hs[nl * 66 + d];
    accd += hv * att_s[h * 130 + d];
    accs += hv * att_s[h * 130 + DD + d];
  }
  if (n < NN) {
    s_dst[n * HH + h] = accd;  // coalesced: index = node0*8 + tid
    s_src[n * HH + h] = accs;
  }
}

// K2: degree counts (4 edges/thread, vectorized dst-row read)
__global__ __launch_bounds__(256) void count_kernel(const int* __restrict__ ei,
                                                    int* __restrict__ counts) {
  int t = blockIdx.x * 256 + threadIdx.x;
  if (t >= EE / 4) return;
  int4 v = ((const int4*)(ei + EE))[t];
  atomicAdd(&counts[v.x], 1);
  atomicAdd(&counts[v.y], 1);
  atomicAdd(&counts[v.z], 1);
  atomicAdd(&counts[v.w], 1);
}

// K3: exclusive scan of counts -> row_start (single block, shfl-based)
__global__ __launch_bounds__(256) void scan_kernel(const int* __restrict__ counts,
                                                   int* __restrict__ row_start) {
  __shared__ int wtot[4];
  int tid = threadIdx.x, lane = tid & 63, wid = tid >> 6;
  int carry = 0;
  const int CHUNK = 256 * 16;  // 4096 elements per pass
  for (int base = 0; base < NN; base += CHUNK) {
    int i0 = base + tid * 16;
    int loc[16];
    int tot = 0;
#pragma unroll
    for (int k = 0; k < 16; ++k) {
      int idx = i0 + k;
      int v = (idx < NN) ? counts[idx] : 0;
      tot += v;
      loc[k] = tot;  // per-thread inclusive
    }
    int incl = tot;
    for (int off = 1; off < 64; off <<= 1) {
      int u = __shfl_up(incl, off);
      if (lane >= off) incl += u;
    }
    if (lane == 63) wtot[wid] = incl;
    __syncthreads();
    int wpre = 0;
    for (int w = 0; w < wid; ++w) wpre += wtot[w];
    int chunk_tot = wtot[0] + wtot[1] + wtot[2] + wtot[3];
    int thread_excl = carry + wpre + (incl - tot);
#pragma unroll
    for (int k = 0; k < 16; ++k) {
      int idx = i0 + k;
      int prev = (k == 0) ? 0 : loc[k - 1];
      if (idx < NN) row_start[idx] = thread_excl + prev;
    }
    carry += chunk_tot;
    __syncthreads();  // before wtot is overwritten next pass
  }
  if (tid == 0) row_start[NN] = carry;  // == EE
}

// K4: CSR bucket fill — scatter SRC node id (K5 never touches edge_index)
__global__ __launch_bounds__(256) void fill_kernel(
    const int* __restrict__ ei, const int* __restrict__ row_start,
    int* __restrict__ fill_ctr, int* __restrict__ sorted_src) {
  int t = blockIdx.x * 256 + threadIdx.x;
  if (t >= EE / 4) return;
  int4 s = ((const int4*)ei)[t];        // src row
  int4 d = ((const int4*)(ei + EE))[t]; // dst row
  int p;
  p = atomicAdd(&fill_ctr[d.x], 1); sorted_src[row_start[d.x] + p] = s.x;
  p = atomicAdd(&fill_ctr[d.y], 1); sorted_src[row_start[d.y] + p] = s.y;
  p = atomicAdd(&fill_ctr[d.z], 1); sorted_src[row_start[d.z] + p] = s.z;
  p = atomicAdd(&fill_ctr[d.w], 1); sorted_src[row_start[d.w] + p] = s.w;
}

// K5: one block per dst node. Fused: scores -> segment max -> exp/denominator
// -> alpha-weighted gather-accumulate -> ELU -> single streamed out write.
// All reductions are LDS-local; zero global atomics.
__global__ __launch_bounds__(256) void fused_kernel(
    const float* __restrict__ h_t, const float* __restrict__ s_dst,
    const float* __restrict__ s_src, const int* __restrict__ row_start,
    const int* __restrict__ sorted_src, float* __restrict__ out) {
  int n = blockIdx.x;
  int tid = threadIdx.x;
  __shared__ float sc_all[CAP][8];   // cached leaky scores
  __shared__ int src_all[CAP];       // cached src ids
  __shared__ float p_chunk[32][8];
  __shared__ float red[256];
  __shared__ int src_s[32];
  __shared__ float sd_s[8], m_s[8], den_s[8], rd_s[8];

  int beg = row_start[n], end = row_start[n + 1];
  int deg = end - beg;
  if (deg == 0) {  // empty segment: reference yields elu(0)=0
    out[(size_t)n * 512 + tid] = 0.f;
    out[(size_t)n * 512 + 256 + tid] = 0.f;
    return;
  }
  bool cached = (deg <= CAP);
  if (tid < 8) {
    sd_s[tid] = s_dst[n * 8 + tid];
    m_s[tid] = -INFINITY;
    den_s[tid] = 0.f;
  }
  __syncthreads();

  int i = tid >> 3, h = tid & 7;
  // ---- phase A: per-head max over this node's edges ----
  for (int b = beg; b < end; b += 32) {
    int cnt = min(32, end - b);
    if (tid < cnt) {
      int s = sorted_src[b + tid];
      src_s[tid] = s;
      if (cached) src_all[b - beg + tid] = s;
    }
    __syncthreads();
    float sc = -INFINITY;
    if (i < cnt) {
      float v = sd_s[h] + s_src[src_s[i] * 8 + h];
      v = v >= 0.f ? v : NEG_SLOPE * v;
      if (cached) sc_all[b - beg + i][h] = v;
      sc = v;
    }
    red[tid] = sc;
    __syncthreads();
#pragma unroll
    for (int s = 128; s >= 8; s >>= 1) {  // strides multiple of 8 keep h fixed
      if (tid < s) red[tid] = fmaxf(red[tid], red[tid + s]);
      __syncthreads();
    }
    if (tid < 8) m_s[tid] = fmaxf(m_s[tid], red[tid]);
    __syncthreads();
  }

  // ---- phase B: p = exp(sc - m), denom sum, weighted accumulate ----
  float acc0 = 0.f, acc1 = 0.f;
  int d = tid & 63, h0 = tid >> 6;  // thread covers heads h0 and h0+4 at dim d
  for (int b = beg; b < end; b += 32) {
    int cnt = min(32, end - b);
    const int* srcp;
    if (cached) {
      srcp = &src_all[b - beg];
    } else {
      if (tid < cnt) src_s[tid] = sorted_src[b + tid];
      srcp = src_s;
    }
    __syncthreads();
    float p = 0.f;
    if (i < cnt) {
      float v;
      if (cached) {
        v = sc_all[b - beg + i][h];
      } else {
        v = sd_s[h] + s_src[srcp[i] * 8 + h];
        v = v >= 0.f ? v : NEG_SLOPE * v;
      }
      p = __expf(v - m_s[h]);
      p_chunk[i][h] = p;
    }
    red[tid] = p;
    __syncthreads();
#pragma unroll
    for (int s = 128; s >= 8; s >>= 1) {
      if (tid < s) red[tid] += red[tid + s];
      __syncthreads();
    }
    if (tid < 8) den_s[tid] += red[tid];
    // p_chunk was written before the tree's first sync -> visible here
    for (int i2 = 0; i2 < cnt; ++i2) {
      float hv = h_t[(size_t)srcp[i2] * 64 + d];  // one row, broadcast x4
      acc0 = fmaf(hv, p_chunk[i2][h0], acc0);
      acc1 = fmaf(hv, p_chunk[i2][h0 + 4], acc1);
    }
    __syncthreads();  // before next chunk overwrites p_chunk/src_s
  }
  if (tid < 8) rd_s[tid] = 1.0f / den_s[tid];  // deg>0 -> den >= 1
  __syncthreads();
  float r0 = acc0 * rd_s[h0];
  float r1 = acc1 * rd_s[h0 + 4];
  r0 = r0 > 0.f ? r0 : expm1f(r0);
  r1 = r1 > 0.f ? r1 : expm1f(r1);
  out[(size_t)n * 512 + tid] = r0;        // element (n, h0, d)
  out[(size_t)n * 512 + 256 + tid] = r1;  // element (n, h0+4, d)
}

extern "C" void kernel_launch(void* const* d_in, const int* in_sizes, int n_in,
                              void* d_out, int out_size, void* d_ws, size_t ws_size,
                              hipStream_t stream) {
  const float* h_t = (const float*)d_in[0];
  const int* ei = (const int*)d_in[1];  // [2, E] int32: row0 = src, row1 = dst
  const float* att = (const float*)d_in[2];
  float* out = (float*)d_out;

  char* ws = (char*)d_ws;
  size_t off = 0;
  auto alloc = [&](size_t bytes) {
    size_t cur = off;
    off += (bytes + 255) & ~(size_t)255;
    return cur;
  };
  float* s_dst = (float*)(ws + alloc((size_t)NN * HH * 4));
  float* s_src = (float*)(ws + alloc((size_t)NN * HH * 4));
  size_t zero_off = off;  // counts + fill_ctr zeroed each call
  int* counts = (int*)(ws + alloc((size_t)NN * 4));
  int* fill_ctr = (int*)(ws + alloc((size_t)NN * 4));
  size_t zero_bytes = off - zero_off;
  int* row_start = (int*)(ws + alloc((size_t)(NN + 1) * 4));
  int* sorted_src = (int*)(ws + alloc((size_t)EE * 4));

  hipMemsetAsync(ws + zero_off, 0, zero_bytes, stream);
  scores_kernel<<<(NN + 31) / 32, 256, 0, stream>>>(h_t, att, s_dst, s_src);
  count_kernel<<<(EE / 4 + 255) / 256, 256, 0, stream>>>(ei, counts);
  scan_kernel<<<1, 256, 0, stream>>>(counts, row_start);
  fill_kernel<<<(EE / 4 + 255) / 256, 256, 0, stream>>>(ei, row_start, fill_ctr,
                                                        sorted_src);
  fused_kernel<<<NN, 256, 0, stream>>>(h_t, s_dst, s_src, row_start, sorted_src,
                                       out);
}

// Round 5
// 262.211 us; speedup vs baseline: 3.5340x; 1.7110x over previous
//
#include <hip/hip_runtime.h>
#include <math.h>

// Problem constants (from reference): N nodes, D feat, H heads, E edges
#define NN 50000
#define DD 64
#define HH 8
#define EE 800000
#define NEG_SLOPE 0.2f
#define WPB 4          // waves (nodes) per block in fused kernel
#define SCAN_B 1024    // elements per scan block
#define NB1 ((NN + SCAN_B - 1) / SCAN_B)  // 49

// K1: per-node scores  s_dst[n,h] = h_t[n,:]·att[h,0:64], s_src = ·att[h,64:128]
__global__ __launch_bounds__(256) void scores_kernel(
    const float* __restrict__ h_t, const float* __restrict__ att,
    float* __restrict__ s_dst, float* __restrict__ s_src) {
  __shared__ float hs[32 * 66];
  __shared__ float att_s[8 * 130];
  int tid = threadIdx.x;
  int node0 = blockIdx.x * 32;
  for (int q = tid; q < HH * 2 * DD; q += 256) {
    int h = q >> 7, k = q & 127;
    att_s[h * 130 + k] = att[q];
  }
  for (int q = tid; q < 32 * DD; q += 256) {
    int nl = q >> 6, d = q & 63;
    hs[nl * 66 + d] = (node0 + nl < NN) ? h_t[(size_t)(node0 + nl) * DD + d] : 0.0f;
  }
  __syncthreads();
  int nl = tid >> 3, h = tid & 7;
  int n = node0 + nl;
  float accd = 0.f, accs = 0.f;
#pragma unroll
  for (int d = 0; d < DD; ++d) {
    float hv = hs[nl * 66 + d];
    accd += hv * att_s[h * 130 + d];
    accs += hv * att_s[h * 130 + DD + d];
  }
  if (n < NN) {
    s_dst[n * HH + h] = accd;
    s_src[n * HH + h] = accs;
  }
}

// K2: degree counts + per-edge intra-segment rank (atomic return value)
__global__ __launch_bounds__(256) void count_kernel(const int* __restrict__ ei,
                                                    int* __restrict__ counts,
                                                    int* __restrict__ rank) {
  int t = blockIdx.x * 256 + threadIdx.x;
  if (t >= EE / 4) return;
  int4 v = ((const int4*)(ei + EE))[t];
  int4 r;
  r.x = atomicAdd(&counts[v.x], 1);
  r.y = atomicAdd(&counts[v.y], 1);
  r.z = atomicAdd(&counts[v.z], 1);
  r.w = atomicAdd(&counts[v.w], 1);
  ((int4*)rank)[t] = r;
}

// K3a: per-block sums of counts
__global__ __launch_bounds__(256) void scan1_kernel(const int* __restrict__ counts,
                                                    int* __restrict__ bsum) {
  int t = threadIdx.x;
  int base = blockIdx.x * SCAN_B + t * 4;
  int s = 0;
  if (base + 3 < NN) {
    int4 v = *(const int4*)(counts + base);
    s = v.x + v.y + v.z + v.w;
  } else {
    for (int k = 0; k < 4; ++k)
      if (base + k < NN) s += counts[base + k];
  }
#pragma unroll
  for (int m = 1; m < 64; m <<= 1) s += __shfl_xor(s, m);
  __shared__ int wsum[4];
  if ((t & 63) == 0) wsum[t >> 6] = s;
  __syncthreads();
  if (t == 0) bsum[blockIdx.x] = wsum[0] + wsum[1] + wsum[2] + wsum[3];
}

// K3b: exclusive scan of NB1 (<=64) block sums, one wave
__global__ void scan2_kernel(const int* __restrict__ bsum, int* __restrict__ boff,
                             int* __restrict__ row_start) {
  int lane = threadIdx.x;
  int v = (lane < NB1) ? bsum[lane] : 0;
  int incl = v;
#pragma unroll
  for (int off = 1; off < 64; off <<= 1) {
    int u = __shfl_up(incl, off);
    if (lane >= off) incl += u;
  }
  if (lane < NB1) boff[lane] = incl - v;
  if (lane == 0) row_start[NN] = EE;
}

// K3c: block-local exclusive scan + block offset -> row_start
__global__ __launch_bounds__(256) void scan3_kernel(const int* __restrict__ counts,
                                                    const int* __restrict__ boff,
                                                    int* __restrict__ row_start) {
  int t = threadIdx.x, lane = t & 63, w = t >> 6;
  int base = blockIdx.x * SCAN_B + t * 4;
  int c[4] = {0, 0, 0, 0};
  bool full = (base + 3 < NN);
  if (full) {
    int4 v = *(const int4*)(counts + base);
    c[0] = v.x; c[1] = v.y; c[2] = v.z; c[3] = v.w;
  } else {
    for (int k = 0; k < 4; ++k)
      if (base + k < NN) c[k] = counts[base + k];
  }
  int tot = c[0] + c[1] + c[2] + c[3];
  int incl = tot;
#pragma unroll
  for (int off = 1; off < 64; off <<= 1) {
    int u = __shfl_up(incl, off);
    if (lane >= off) incl += u;
  }
  __shared__ int wt[4];
  if (lane == 63) wt[w] = incl;
  __syncthreads();
  int wpre = 0;
  for (int q = 0; q < w; ++q) wpre += wt[q];
  int p = boff[blockIdx.x] + wpre + incl - tot;
  int o0 = p, o1 = p + c[0], o2 = o1 + c[1], o3 = o2 + c[2];
  if (full) {
    *(int4*)(row_start + base) = make_int4(o0, o1, o2, o3);
  } else {
    int o[4] = {o0, o1, o2, o3};
    for (int k = 0; k < 4; ++k)
      if (base + k < NN) row_start[base + k] = o[k];
  }
}

// K4: CSR bucket fill (pure streaming, no atomics)
__global__ __launch_bounds__(256) void fill_kernel(
    const int* __restrict__ ei, const int* __restrict__ row_start,
    const int* __restrict__ rank, int* __restrict__ sorted_src) {
  int t = blockIdx.x * 256 + threadIdx.x;
  if (t >= EE / 4) return;
  int4 s = ((const int4*)ei)[t];
  int4 d = ((const int4*)(ei + EE))[t];
  int4 r = ((const int4*)rank)[t];
  sorted_src[row_start[d.x] + r.x] = s.x;
  sorted_src[row_start[d.y] + r.y] = s.y;
  sorted_src[row_start[d.z] + r.z] = s.z;
  sorted_src[row_start[d.w] + r.w] = s.w;
}

// K5: ONE WAVE PER NODE. Wave-synchronous: shfl butterflies for max/denominator,
// per-wave LDS for p/src broadcast, deferred division, fused ELU. No barriers.
__global__ __launch_bounds__(256) void fused_kernel(
    const float* __restrict__ h_t, const float* __restrict__ s_dst,
    const float* __restrict__ s_src, const int* __restrict__ row_start,
    const int* __restrict__ sorted_src, float* __restrict__ out) {
  __shared__ float p_lds[WPB][64][8];
  __shared__ int src_lds[WPB][64];
  int w = threadIdx.x >> 6, lane = threadIdx.x & 63;
  int n = blockIdx.x * WPB + w;
  if (n >= NN) return;
  float (*pw)[8] = p_lds[w];
  int* sw = src_lds[w];
  int beg = row_start[n], end = row_start[n + 1];
  int deg = end - beg;
  size_t ob = (size_t)n * 512 + lane;
  if (deg == 0) {  // reference: elu(0) = 0
#pragma unroll
    for (int h = 0; h < 8; ++h) out[ob + h * 64] = 0.f;
    return;
  }
  int i = lane >> 3, hh = lane & 7;  // score-phase role: edge-slot i, head hh
  float sd = s_dst[n * 8 + hh];
  float m = -INFINITY, sum = 0.f;
  float acc[8];
#pragma unroll
  for (int h = 0; h < 8; ++h) acc[h] = 0.f;

  if (deg <= 64) {
    float v[8];
    int sreg[8];
#pragma unroll
    for (int k = 0; k < 8; ++k) {
      int e = i + 8 * k;
      if (e < deg) {
        int s = sorted_src[beg + e];
        sreg[k] = s;
        float x = sd + s_src[s * 8 + hh];
        x = x >= 0.f ? x : NEG_SLOPE * x;
        v[k] = x;
        m = fmaxf(m, x);
      }
    }
#pragma unroll
    for (int msk = 8; msk < 64; msk <<= 1) m = fmaxf(m, __shfl_xor(m, msk));
#pragma unroll
    for (int k = 0; k < 8; ++k) {
      int e = i + 8 * k;
      if (e < deg) {
        float p = __expf(v[k] - m);
        sum += p;
        pw[e][hh] = p;                 // byte off = lane*4 + k*256: conflict-free
        if (hh == 0) sw[e] = sreg[k];
      }
    }
#pragma unroll
    for (int msk = 8; msk < 64; msk <<= 1) sum += __shfl_xor(sum, msk);
    __builtin_amdgcn_wave_barrier();   // keep LDS writes ordered before reads
    for (int e = 0; e < deg; ++e) {    // accumulate role: lane = d
      int s = sw[e];
      float hv = h_t[(size_t)s * 64 + lane];   // coalesced 256B row
      float4 pa = *(const float4*)&pw[e][0];   // broadcast reads
      float4 pb = *(const float4*)&pw[e][4];
      acc[0] = fmaf(hv, pa.x, acc[0]);
      acc[1] = fmaf(hv, pa.y, acc[1]);
      acc[2] = fmaf(hv, pa.z, acc[2]);
      acc[3] = fmaf(hv, pa.w, acc[3]);
      acc[4] = fmaf(hv, pb.x, acc[4]);
      acc[5] = fmaf(hv, pb.y, acc[5]);
      acc[6] = fmaf(hv, pb.z, acc[6]);
      acc[7] = fmaf(hv, pb.w, acc[7]);
    }
  } else {
    // rare fallback (deg > 64): two-pass with per-chunk recompute
    for (int c = 0; c < deg; c += 64) {
      int cnt = min(64, deg - c);
#pragma unroll
      for (int k = 0; k < 8; ++k) {
        int le = i + 8 * k;
        if (le < cnt) {
          int s = sorted_src[beg + c + le];
          float x = sd + s_src[s * 8 + hh];
          x = x >= 0.f ? x : NEG_SLOPE * x;
          m = fmaxf(m, x);
        }
      }
    }
#pragma unroll
    for (int msk = 8; msk < 64; msk <<= 1) m = fmaxf(m, __shfl_xor(m, msk));
    for (int c = 0; c < deg; c += 64) {
      int cnt = min(64, deg - c);
      __builtin_amdgcn_wave_barrier();
#pragma unroll
      for (int k = 0; k < 8; ++k) {
        int le = i + 8 * k;
        if (le < cnt) {
          int s = sorted_src[beg + c + le];
          float x = sd + s_src[s * 8 + hh];
          x = x >= 0.f ? x : NEG_SLOPE * x;
          float p = __expf(x - m);
          sum += p;
          pw[le][hh] = p;
          if (hh == 0) sw[le] = s;
        }
      }
      __builtin_amdgcn_wave_barrier();
      for (int e = 0; e < cnt; ++e) {
        int s = sw[e];
        float hv = h_t[(size_t)s * 64 + lane];
        float4 pa = *(const float4*)&pw[e][0];
        float4 pb = *(const float4*)&pw[e][4];
        acc[0] = fmaf(hv, pa.x, acc[0]);
        acc[1] = fmaf(hv, pa.y, acc[1]);
        acc[2] = fmaf(hv, pa.z, acc[2]);
        acc[3] = fmaf(hv, pa.w, acc[3]);
        acc[4] = fmaf(hv, pb.x, acc[4]);
        acc[5] = fmaf(hv, pb.y, acc[5]);
        acc[6] = fmaf(hv, pb.z, acc[6]);
        acc[7] = fmaf(hv, pb.w, acc[7]);
      }
    }
#pragma unroll
    for (int msk = 8; msk < 64; msk <<= 1) sum += __shfl_xor(sum, msk);
  }
  // epilogue: rd for head h lives in lane h (lane&7==h); broadcast via shfl
  float rdv = 1.0f / sum;
#pragma unroll
  for (int h = 0; h < 8; ++h) {
    float rd = __shfl(rdv, h);
    float r = acc[h] * rd;
    r = r > 0.f ? r : expm1f(r);
    out[ob + h * 64] = r;
  }
}

extern "C" void kernel_launch(void* const* d_in, const int* in_sizes, int n_in,
                              void* d_out, int out_size, void* d_ws, size_t ws_size,
                              hipStream_t stream) {
  const float* h_t = (const float*)d_in[0];
  const int* ei = (const int*)d_in[1];  // [2, E] int32: row0 = src, row1 = dst
  const float* att = (const float*)d_in[2];
  float* out = (float*)d_out;

  char* ws = (char*)d_ws;
  size_t off = 0;
  auto alloc = [&](size_t bytes) {
    size_t cur = off;
    off += (bytes + 255) & ~(size_t)255;
    return cur;
  };
  float* s_dst = (float*)(ws + alloc((size_t)NN * HH * 4));
  float* s_src = (float*)(ws + alloc((size_t)NN * HH * 4));
  size_t zero_off = off;
  int* counts = (int*)(ws + alloc((size_t)NN * 4));
  size_t zero_bytes = off - zero_off;
  int* row_start = (int*)(ws + alloc((size_t)(NN + 1) * 4));
  int* sorted_src = (int*)(ws + alloc((size_t)EE * 4));
  int* rank = (int*)(ws + alloc((size_t)EE * 4));
  int* bsum = (int*)(ws + alloc((size_t)NB1 * 4));
  int* boff = (int*)(ws + alloc((size_t)NB1 * 4));

  hipMemsetAsync(ws + zero_off, 0, zero_bytes, stream);
  scores_kernel<<<(NN + 31) / 32, 256, 0, stream>>>(h_t, att, s_dst, s_src);
  count_kernel<<<(EE / 4 + 255) / 256, 256, 0, stream>>>(ei, counts, rank);
  scan1_kernel<<<NB1, 256, 0, stream>>>(counts, bsum);
  scan2_kernel<<<1, 64, 0, stream>>>(bsum, boff, row_start);
  scan3_kernel<<<NB1, 256, 0, stream>>>(counts, boff, row_start);
  fill_kernel<<<(EE / 4 + 255) / 256, 256, 0, stream>>>(ei, row_start, rank,
                                                        sorted_src);
  fused_kernel<<<NN / WPB, 256, 0, stream>>>(h_t, s_dst, s_src, row_start,
                                             sorted_src, out);
}